// Round 3
// baseline (572.320 us; speedup 1.0000x reference)
//
#include <hip/hip_runtime.h>
#include <hip/hip_bf16.h>

#define EMB   1024
#define NHEAD 16
#define HDIM  64
#define BSZ   4
#define SEQ   2048
#define MROWS (BSZ*SEQ)     // 8192
#define NQKV  (3*EMB)       // 3072

typedef __bf16 bf16;
typedef __bf16 bf16v8 __attribute__((ext_vector_type(8)));
typedef float  f32v4  __attribute__((ext_vector_type(4)));

#define MFMA16(a,b,c) __builtin_amdgcn_mfma_f32_16x16x32_bf16((a),(b),(c),0,0,0)

__device__ __forceinline__ void gload_lds16(const bf16* g, bf16* l) {
  __builtin_amdgcn_global_load_lds((const __attribute__((address_space(1))) void*)g,
                                   (__attribute__((address_space(3))) void*)l,
                                   16, 0, 0);
}

// ---------------- scale reduction + ternarize + split ----------------

__global__ void zero2_kernel(float* p) { p[threadIdx.x] = 0.f; }

__global__ void abs_sum_kernel(const float* __restrict__ w, int n, float* out) {
  float s = 0.f;
  for (int i = blockIdx.x * blockDim.x + threadIdx.x; i < n; i += gridDim.x * blockDim.x)
    s += fabsf(w[i]);
  #pragma unroll
  for (int off = 32; off; off >>= 1) s += __shfl_down(s, off, 64);
  __shared__ float red[4];
  int lane = threadIdx.x & 63, wid = threadIdx.x >> 6;
  if (lane == 0) red[wid] = s;
  __syncthreads();
  if (threadIdx.x == 0) atomicAdd(out, red[0] + red[1] + red[2] + red[3]);
}

__global__ void ternarize_kernel(const float* __restrict__ w, int n,
                                 const float* __restrict__ sum, bf16* __restrict__ out) {
  int i = blockIdx.x * blockDim.x + threadIdx.x;
  if (i >= n) return;
  float scale = fmaxf(*sum / (float)n, 1e-8f);
  float t = rintf(w[i] / scale);          // RNE == jnp.round
  t = fmaxf(-1.f, fminf(1.f, t));
  out[i] = (bf16)t;                        // {-1,0,1} exact in bf16
}

__global__ void split_x_kernel(const float* __restrict__ x, bf16* __restrict__ xh,
                               bf16* __restrict__ xl, int n) {
  int i = blockIdx.x * blockDim.x + threadIdx.x;
  if (i >= n) return;
  float v = x[i];
  bf16 h = (bf16)v;
  xh[i] = h;
  xl[i] = (bf16)(v - (float)h);
}

// ---------------- QKV GEMM ----------------
// Epilogue now pre-scales q by 0.125*log2(e): scores exit QK^T MFMA already
// in log2 domain -> attn softmax needs no per-element multiplies.

__launch_bounds__(256, 2)
__global__ void gemm_qkv_kernel(const bf16* __restrict__ xh, const bf16* __restrict__ xl,
                                const bf16* __restrict__ wt,
                                bf16* __restrict__ qh, bf16* __restrict__ ql,
                                bf16* __restrict__ kh, bf16* __restrict__ kl,
                                bf16* __restrict__ vv) {
  __shared__ __align__(16) bf16 Ah[128 * 64];
  __shared__ __align__(16) bf16 Al[128 * 64];
  __shared__ __align__(16) bf16 Bs[128 * 64];
  const int tid = threadIdx.x;
  const int lane = tid & 63, wid = tid >> 6;
  const int quad = lane >> 4, l16 = lane & 15;
  const int m0 = blockIdx.x * 128, n0 = blockIdx.y * 128;
  const int wm = (wid >> 1) * 64, wn = (wid & 1) * 64;
  f32v4 acc[4][4] = {};

  for (int kt = 0; kt < EMB / 64; ++kt) {
    __syncthreads();
    #pragma unroll
    for (int r = 0; r < 4; ++r) {
      int li = r * 256 + tid;
      int row = li >> 3, col = (li & 7) * 8;
      gload_lds16(xh + (size_t)(m0 + row) * EMB + kt * 64 + col, &Ah[li * 8]);
      gload_lds16(xl + (size_t)(m0 + row) * EMB + kt * 64 + col, &Al[li * 8]);
      gload_lds16(wt + (size_t)(n0 + row) * EMB + kt * 64 + col, &Bs[li * 8]);
    }
    __syncthreads();
    #pragma unroll
    for (int kk = 0; kk < 2; ++kk) {
      bf16v8 af[4], alf[4], bfr[4];
      #pragma unroll
      for (int i = 0; i < 4; ++i) {
        af[i]  = *(const bf16v8*)&Ah[(wm + i * 16 + l16) * 64 + kk * 32 + quad * 8];
        alf[i] = *(const bf16v8*)&Al[(wm + i * 16 + l16) * 64 + kk * 32 + quad * 8];
        bfr[i] = *(const bf16v8*)&Bs[(wn + i * 16 + l16) * 64 + kk * 32 + quad * 8];
      }
      #pragma unroll
      for (int i = 0; i < 4; ++i)
        #pragma unroll
        for (int j = 0; j < 4; ++j) {
          acc[i][j] = MFMA16(af[i],  bfr[j], acc[i][j]);
          acc[i][j] = MFMA16(alf[i], bfr[j], acc[i][j]);
        }
    }
  }
  const float QSCALE = 0.18033688011112042f;   // 0.125 * log2(e)
  #pragma unroll
  for (int i = 0; i < 4; ++i)
    #pragma unroll
    for (int j = 0; j < 4; ++j)
      #pragma unroll
      for (int r = 0; r < 4; ++r) {
        int m = m0 + wm + i * 16 + quad * 4 + r;
        int n = n0 + wn + j * 16 + l16;
        float c = acc[i][j][r];
        int b = m >> 11, t = m & (SEQ - 1);
        int region = n >> 10, c1 = n & 1023, h = c1 >> 6, d = c1 & 63;
        size_t idx = (((size_t)(b * NHEAD + h) * SEQ + t) << 6) + d;
        if (region == 0)      { float cs = c * QSCALE; bf16 hi = (bf16)cs; qh[idx] = hi; ql[idx] = (bf16)(cs - (float)hi); }
        else if (region == 1) { bf16 hi = (bf16)c; kh[idx] = hi; kl[idx] = (bf16)(c - (float)hi); }
        else                  { vv[idx] = (bf16)c; }
      }
}

// ---------------- V transpose: [B,H,T,D] -> [B,H,D,T] ----------------

__global__ void transpose_v_kernel(const bf16* __restrict__ v, bf16* __restrict__ vt) {
  __shared__ bf16 tile[64 * 72];
  const int tid = threadIdx.x;
  const int bh = blockIdx.y, t0 = blockIdx.x * 64;
  const size_t base = (size_t)bh * SEQ * HDIM;
  #pragma unroll
  for (int r = 0; r < 2; ++r) {
    int li = r * 256 + tid;
    int row = li >> 3, col = (li & 7) * 8;
    bf16v8 val = *(const bf16v8*)(v + base + (size_t)(t0 + row) * HDIM + col);
    #pragma unroll
    for (int j = 0; j < 8; ++j) tile[(col + j) * 72 + row] = val[j];
  }
  __syncthreads();
  #pragma unroll
  for (int r = 0; r < 2; ++r) {
    int li = r * 256 + tid;
    int drow = li >> 3, tcol = (li & 7) * 8;
    bf16v8 val;
    #pragma unroll
    for (int j = 0; j < 8; ++j) val[j] = tile[drow * 72 + tcol + j];
    *(bf16v8*)(vt + base + (size_t)drow * SEQ + t0 + tcol) = val;
  }
}

// ---------------- Flash attention v3 ----------------
// 512 threads = 8 waves, Q-tile 128, KV tile 64.
// LDS overlay: Q region (32 KB) is dead after the one-time fragment read, so
// K/Kl/Vt/Pw alias it -> 41 KB/block -> 3 blocks/CU (24 waves/CU).
// Row-sums via ones-column MFMA (extra accumulator, same alpha rescale) ->
// no per-tile shuffle-sum chains. Scores arrive pre-scaled in log2 domain.

__launch_bounds__(512, 6)
__global__ void attn_kernel(const bf16* __restrict__ qh, const bf16* __restrict__ ql,
                            const bf16* __restrict__ kh, const bf16* __restrict__ kl,
                            const bf16* __restrict__ vt, bf16* __restrict__ o) {
  __shared__ __align__(16) char smem[41984];
  bf16* Qh = (bf16*)smem;               // 16384 B   (Q phase)
  bf16* Ql = (bf16*)(smem + 16384);     // 16384 B
  bf16* Kh = (bf16*)smem;               // 8192 B    (K phase, aliases Q)
  bf16* Kl = (bf16*)(smem + 8192);      // 8192 B
  bf16* Vt = (bf16*)(smem + 16384);     // 8192 B
  bf16* Pw = (bf16*)(smem + 24576);     // 8 waves * 16*68*2 = 17408 B
  const int tid = threadIdx.x;
  const int lane = tid & 63, wid = tid >> 6;
  const int quad = lane >> 4, l16 = lane & 15;
  const int xs = l16 & 7;
  const int bh = blockIdx.y;
  const int qt = (int)gridDim.x - 1 - (int)blockIdx.x;   // heavy first
  const int q0 = qt * 128;
  const size_t base = (size_t)bh * SEQ * HDIM;

  // stage Q (hi+lo), swizzled
  #pragma unroll
  for (int r = 0; r < 2; ++r) {
    int li = r * 512 + tid;
    int row = li >> 3, cg = (li & 7) ^ (row & 7);
    gload_lds16(qh + base + (size_t)(q0 + row) * HDIM + cg * 8, &Qh[li * 8]);
    gload_lds16(ql + base + (size_t)(q0 + row) * HDIM + cg * 8, &Ql[li * 8]);
  }
  __syncthreads();
  bf16v8 qhf[2], qlf[2];
  #pragma unroll
  for (int kk = 0; kk < 2; ++kk) {
    int off = (wid * 16 + l16) * 64 + (((kk << 2) | quad) ^ xs) * 8;
    qhf[kk] = *(const bf16v8*)&Qh[off];
    qlf[kk] = *(const bf16v8*)&Ql[off];
  }

  bf16v8 ones_f;
  {
    bf16 v1 = (l16 == 0) ? (bf16)1.0f : (bf16)0.0f;
    #pragma unroll
    for (int j = 0; j < 8; ++j) ones_f[j] = v1;
  }

  f32v4 oacc[4] = {};
  f32v4 lacc = {};
  float mrow[4];
  #pragma unroll
  for (int r = 0; r < 4; ++r) mrow[r] = -1e30f;

  const int qrow_hi = q0 + wid * 16 + 15;       // wave-uniform causal limit
  const int ntiles = 2 * qt + 2;
  for (int ktile = 0; ktile < ntiles; ++ktile) {
    const int k0 = ktile * 64;
    __syncthreads();                            // also protects Q->K overlay on iter 0
    {
      int row = tid >> 3, cg = (tid & 7) ^ (row & 7);
      gload_lds16(kh + base + (size_t)(k0 + row) * HDIM + cg * 8, &Kh[(size_t)tid * 8]);
      gload_lds16(kl + base + (size_t)(k0 + row) * HDIM + cg * 8, &Kl[(size_t)tid * 8]);
      gload_lds16(vt + base + (size_t)row * SEQ + k0 + cg * 8,    &Vt[(size_t)tid * 8]);
    }
    __syncthreads();
    if (k0 > qrow_hi) continue;                  // fully-masked tile for this wave

    f32v4 sacc[4] = {};
    #pragma unroll
    for (int kk = 0; kk < 2; ++kk) {
      const int co = (((kk << 2) | quad) ^ xs) * 8;
      bf16v8 khf[4], klf[4];
      #pragma unroll
      for (int nt = 0; nt < 4; ++nt) {
        khf[nt] = *(const bf16v8*)&Kh[(nt * 16 + l16) * 64 + co];
        klf[nt] = *(const bf16v8*)&Kl[(nt * 16 + l16) * 64 + co];
      }
      #pragma unroll
      for (int nt = 0; nt < 4; ++nt) {
        sacc[nt] = MFMA16(qhf[kk], khf[nt], sacc[nt]);
        sacc[nt] = MFMA16(qhf[kk], klf[nt], sacc[nt]);
        sacc[nt] = MFMA16(qlf[kk], khf[nt], sacc[nt]);
      }
    }

    // mask (scores already in log2 domain)
    const int qrow_base = q0 + wid * 16 + quad * 4;
    #pragma unroll
    for (int nt = 0; nt < 4; ++nt) {
      int key = k0 + nt * 16 + l16;
      #pragma unroll
      for (int r = 0; r < 4; ++r)
        if (key > qrow_base + r) sacc[nt][r] = -1e30f;
    }
    float mnew[4], alpha[4];
    #pragma unroll
    for (int r = 0; r < 4; ++r) {
      float mx = fmaxf(fmaxf(sacc[0][r], sacc[1][r]), fmaxf(sacc[2][r], sacc[3][r]));
      #pragma unroll
      for (int off = 8; off; off >>= 1) mx = fmaxf(mx, __shfl_xor(mx, off, 64));
      mnew[r] = fmaxf(mrow[r], mx);
      alpha[r] = __builtin_amdgcn_exp2f(mrow[r] - mnew[r]);
      mrow[r] = mnew[r];
    }
    bf16* pwave = Pw + wid * (16 * 68);
    #pragma unroll
    for (int nt = 0; nt < 4; ++nt)
      #pragma unroll
      for (int r = 0; r < 4; ++r)
        pwave[(quad * 4 + r) * 68 + nt * 16 + l16] =
            (bf16)__builtin_amdgcn_exp2f(sacc[nt][r] - mnew[r]);
    #pragma unroll
    for (int r = 0; r < 4; ++r) {
      lacc[r] *= alpha[r];
      #pragma unroll
      for (int dt = 0; dt < 4; ++dt) oacc[dt][r] *= alpha[r];
    }

    // PV + row-sum (ones-column): A = P (wave-private LDS slice)
    #pragma unroll
    for (int kk = 0; kk < 2; ++kk) {
      bf16v8 pf = *(const bf16v8*)&pwave[l16 * 68 + kk * 32 + quad * 8];
      const int co = (((kk << 2) | quad) ^ xs) * 8;
      lacc = MFMA16(pf, ones_f, lacc);
      #pragma unroll
      for (int dt = 0; dt < 4; ++dt) {
        bf16v8 vf = *(const bf16v8*)&Vt[(dt * 16 + l16) * 64 + co];
        oacc[dt] = MFMA16(pf, vf, oacc[dt]);
      }
    }
  }

  // row-sum lives in column 0 (lane l16==0 of each quad) -> broadcast
  float lrow[4];
  #pragma unroll
  for (int r = 0; r < 4; ++r) lrow[r] = __shfl(lacc[r], lane & 48, 64);

  const int b = bh >> 4, h = bh & 15;
  #pragma unroll
  for (int dt = 0; dt < 4; ++dt)
    #pragma unroll
    for (int r = 0; r < 4; ++r) {
      int q = q0 + wid * 16 + quad * 4 + r;
      int d = dt * 16 + l16;
      float val = oacc[dt][r] / lrow[r];
      o[((size_t)(b * SEQ + q)) * EMB + h * HDIM + d] = (bf16)val;
    }
}

// ---------------- out projection (unchanged) ----------------

__launch_bounds__(256, 2)
__global__ void gemm_out_kernel(const bf16* __restrict__ oin, const bf16* __restrict__ wt,
                                float* __restrict__ out) {
  __shared__ __align__(16) bf16 As_[128 * 64];
  __shared__ __align__(16) bf16 Bs_[128 * 64];
  const int tid = threadIdx.x;
  const int lane = tid & 63, wid = tid >> 6;
  const int quad = lane >> 4, l16 = lane & 15;
  const int m0 = blockIdx.x * 128, n0 = blockIdx.y * 128;
  const int wm = (wid >> 1) * 64, wn = (wid & 1) * 64;
  f32v4 acc[4][4] = {};

  for (int kt = 0; kt < EMB / 64; ++kt) {
    __syncthreads();
    #pragma unroll
    for (int r = 0; r < 4; ++r) {
      int li = r * 256 + tid;
      int row = li >> 3, col = (li & 7) * 8;
      gload_lds16(oin + (size_t)(m0 + row) * EMB + kt * 64 + col, &As_[li * 8]);
      gload_lds16(wt  + (size_t)(n0 + row) * EMB + kt * 64 + col, &Bs_[li * 8]);
    }
    __syncthreads();
    #pragma unroll
    for (int kk = 0; kk < 2; ++kk) {
      bf16v8 af[4], bfr[4];
      #pragma unroll
      for (int i = 0; i < 4; ++i) {
        af[i]  = *(const bf16v8*)&As_[(wm + i * 16 + l16) * 64 + kk * 32 + quad * 8];
        bfr[i] = *(const bf16v8*)&Bs_[(wn + i * 16 + l16) * 64 + kk * 32 + quad * 8];
      }
      #pragma unroll
      for (int i = 0; i < 4; ++i)
        #pragma unroll
        for (int j = 0; j < 4; ++j)
          acc[i][j] = MFMA16(af[i], bfr[j], acc[i][j]);
    }
  }
  #pragma unroll
  for (int i = 0; i < 4; ++i)
    #pragma unroll
    for (int j = 0; j < 4; ++j)
      #pragma unroll
      for (int r = 0; r < 4; ++r) {
        int m = m0 + wm + i * 16 + quad * 4 + r;
        int n = n0 + wn + j * 16 + l16;
        out[(size_t)m * EMB + n] = acc[i][j][r];
      }
}

// ---------------- launch ----------------

extern "C" void kernel_launch(void* const* d_in, const int* in_sizes, int n_in,
                              void* d_out, int out_size, void* d_ws, size_t ws_size,
                              hipStream_t stream) {
  const float* x     = (const float*)d_in[0];
  const float* w_qkv = (const float*)d_in[1];
  const float* w_out = (const float*)d_in[2];
  float* out = (float*)d_out;
  char* ws = (char*)d_ws;

  const size_t SZ = (size_t)MROWS * EMB * sizeof(bf16);   // 16.78 MB
  size_t off = 0;
  float* sums = (float*)ws;            off = 256;
  bf16* wq_t = (bf16*)(ws + off);      off += (size_t)NQKV * EMB * sizeof(bf16);
  bf16* wo_t = (bf16*)(ws + off);      off += (size_t)EMB * EMB * sizeof(bf16);
  bf16* xh   = (bf16*)(ws + off);      off += SZ;
  bf16* xl   = (bf16*)(ws + off);      off += SZ;
  bf16* qh   = (bf16*)(ws + off);      off += SZ;
  bf16* ql   = (bf16*)(ws + off);      off += SZ;
  bf16* kh   = (bf16*)(ws + off);      off += SZ;
  bf16* kl   = (bf16*)(ws + off);      off += SZ;
  bf16* vv   = (bf16*)(ws + off);      off += SZ;
  bf16* vt   = xh;   // x dead after gemm_qkv -> reuse
  bf16* ob   = xl;   // attention output (bf16), reuse
  (void)in_sizes; (void)n_in; (void)out_size; (void)ws_size;

  zero2_kernel<<<1, 2, 0, stream>>>(sums);
  abs_sum_kernel<<<256, 256, 0, stream>>>(w_qkv, NQKV * EMB, &sums[0]);
  abs_sum_kernel<<<256, 256, 0, stream>>>(w_out, EMB * EMB, &sums[1]);
  ternarize_kernel<<<(NQKV * EMB) / 256, 256, 0, stream>>>(w_qkv, NQKV * EMB, &sums[0], wq_t);
  ternarize_kernel<<<(EMB * EMB) / 256, 256, 0, stream>>>(w_out, EMB * EMB, &sums[1], wo_t);
  split_x_kernel<<<(MROWS * EMB) / 256, 256, 0, stream>>>(x, xh, xl, MROWS * EMB);
  gemm_qkv_kernel<<<dim3(MROWS / 128, NQKV / 128), 256, 0, stream>>>(xh, xl, wq_t, qh, ql, kh, kl, vv);
  transpose_v_kernel<<<dim3(SEQ / 64, BSZ * NHEAD), 256, 0, stream>>>(vv, vt);
  attn_kernel<<<dim3(SEQ / 128, BSZ * NHEAD), 512, 0, stream>>>(qh, ql, kh, kl, vt, ob);
  gemm_out_kernel<<<dim3(MROWS / 128, EMB / 128), 256, 0, stream>>>(ob, wo_t, out);
}

// Round 4
// 482.348 us; speedup vs baseline: 1.1865x; 1.1865x over previous
//
#include <hip/hip_runtime.h>
#include <hip/hip_bf16.h>

#define EMB   1024
#define NHEAD 16
#define HDIM  64
#define BSZ   4
#define SEQ   2048
#define MROWS (BSZ*SEQ)     // 8192
#define NQKV  (3*EMB)       // 3072

typedef __bf16 bf16;
typedef __bf16 bf16v8 __attribute__((ext_vector_type(8)));
typedef float  f32v4  __attribute__((ext_vector_type(4)));

#define MFMA16(a,b,c) __builtin_amdgcn_mfma_f32_16x16x32_bf16((a),(b),(c),0,0,0)

__device__ __forceinline__ void gload_lds16(const bf16* g, bf16* l) {
  __builtin_amdgcn_global_load_lds((const __attribute__((address_space(1))) void*)g,
                                   (__attribute__((address_space(3))) void*)l,
                                   16, 0, 0);
}

// ---------------- scale reduction + ternarize + split ----------------

__global__ void zero2_kernel(float* p) { p[threadIdx.x] = 0.f; }

__global__ void abs_sum_kernel(const float* __restrict__ w, int n, float* out) {
  float s = 0.f;
  for (int i = blockIdx.x * blockDim.x + threadIdx.x; i < n; i += gridDim.x * blockDim.x)
    s += fabsf(w[i]);
  #pragma unroll
  for (int off = 32; off; off >>= 1) s += __shfl_down(s, off, 64);
  __shared__ float red[4];
  int lane = threadIdx.x & 63, wid = threadIdx.x >> 6;
  if (lane == 0) red[wid] = s;
  __syncthreads();
  if (threadIdx.x == 0) atomicAdd(out, red[0] + red[1] + red[2] + red[3]);
}

__global__ void ternarize_kernel(const float* __restrict__ w, int n,
                                 const float* __restrict__ sum, bf16* __restrict__ out) {
  int i = blockIdx.x * blockDim.x + threadIdx.x;
  if (i >= n) return;
  float scale = fmaxf(*sum / (float)n, 1e-8f);
  float t = rintf(w[i] / scale);          // RNE == jnp.round
  t = fmaxf(-1.f, fminf(1.f, t));
  out[i] = (bf16)t;                        // {-1,0,1} exact in bf16
}

__global__ void split_x_kernel(const float* __restrict__ x, bf16* __restrict__ xh,
                               bf16* __restrict__ xl, int n) {
  int i = blockIdx.x * blockDim.x + threadIdx.x;
  if (i >= n) return;
  float v = x[i];
  bf16 h = (bf16)v;
  xh[i] = h;
  xl[i] = (bf16)(v - (float)h);
}

// ---------------- QKV GEMM ----------------
// q pre-scaled by 0.125*log2(e) so attn softmax works directly in log2 domain.
// v-region blocks (n0 >= 2048, block-uniform) skip the lo-half A staging and
// MFMAs: v only needs single-bf16 accuracy (it feeds bf16 PV anyway).

__launch_bounds__(256, 2)
__global__ void gemm_qkv_kernel(const bf16* __restrict__ xh, const bf16* __restrict__ xl,
                                const bf16* __restrict__ wt,
                                bf16* __restrict__ qh, bf16* __restrict__ ql,
                                bf16* __restrict__ kh, bf16* __restrict__ kl,
                                bf16* __restrict__ vv) {
  __shared__ __align__(16) bf16 Ah[128 * 64];
  __shared__ __align__(16) bf16 Al[128 * 64];
  __shared__ __align__(16) bf16 Bs[128 * 64];
  const int tid = threadIdx.x;
  const int lane = tid & 63, wid = tid >> 6;
  const int quad = lane >> 4, l16 = lane & 15;
  const int m0 = blockIdx.x * 128, n0 = blockIdx.y * 128;
  const int wm = (wid >> 1) * 64, wn = (wid & 1) * 64;
  const bool vblk = (n0 >= 2 * EMB);       // block-uniform
  f32v4 acc[4][4] = {};

  for (int kt = 0; kt < EMB / 64; ++kt) {
    __syncthreads();
    #pragma unroll
    for (int r = 0; r < 4; ++r) {
      int li = r * 256 + tid;
      int row = li >> 3, col = (li & 7) * 8;
      gload_lds16(xh + (size_t)(m0 + row) * EMB + kt * 64 + col, &Ah[li * 8]);
      if (!vblk)
        gload_lds16(xl + (size_t)(m0 + row) * EMB + kt * 64 + col, &Al[li * 8]);
      gload_lds16(wt + (size_t)(n0 + row) * EMB + kt * 64 + col, &Bs[li * 8]);
    }
    __syncthreads();
    #pragma unroll
    for (int kk = 0; kk < 2; ++kk) {
      bf16v8 af[4], alf[4], bfr[4];
      #pragma unroll
      for (int i = 0; i < 4; ++i) {
        af[i]  = *(const bf16v8*)&Ah[(wm + i * 16 + l16) * 64 + kk * 32 + quad * 8];
        if (!vblk)
          alf[i] = *(const bf16v8*)&Al[(wm + i * 16 + l16) * 64 + kk * 32 + quad * 8];
        bfr[i] = *(const bf16v8*)&Bs[(wn + i * 16 + l16) * 64 + kk * 32 + quad * 8];
      }
      #pragma unroll
      for (int i = 0; i < 4; ++i)
        #pragma unroll
        for (int j = 0; j < 4; ++j) {
          acc[i][j] = MFMA16(af[i], bfr[j], acc[i][j]);
          if (!vblk) acc[i][j] = MFMA16(alf[i], bfr[j], acc[i][j]);
        }
    }
  }
  const float QSCALE = 0.18033688011112042f;   // 0.125 * log2(e)
  #pragma unroll
  for (int i = 0; i < 4; ++i)
    #pragma unroll
    for (int j = 0; j < 4; ++j)
      #pragma unroll
      for (int r = 0; r < 4; ++r) {
        int m = m0 + wm + i * 16 + quad * 4 + r;
        int n = n0 + wn + j * 16 + l16;
        float c = acc[i][j][r];
        int b = m >> 11, t = m & (SEQ - 1);
        int region = n >> 10, c1 = n & 1023, h = c1 >> 6, d = c1 & 63;
        size_t idx = (((size_t)(b * NHEAD + h) * SEQ + t) << 6) + d;
        if (region == 0)      { float cs = c * QSCALE; bf16 hi = (bf16)cs; qh[idx] = hi; ql[idx] = (bf16)(cs - (float)hi); }
        else if (region == 1) { bf16 hi = (bf16)c; kh[idx] = hi; kl[idx] = (bf16)(c - (float)hi); }
        else                  { vv[idx] = (bf16)c; }
      }
}

// ---------------- V transpose: [B,H,T,D] -> [B,H,D,T] ----------------

__global__ void transpose_v_kernel(const bf16* __restrict__ v, bf16* __restrict__ vt) {
  __shared__ bf16 tile[64 * 72];
  const int tid = threadIdx.x;
  const int bh = blockIdx.y, t0 = blockIdx.x * 64;
  const size_t base = (size_t)bh * SEQ * HDIM;
  #pragma unroll
  for (int r = 0; r < 2; ++r) {
    int li = r * 256 + tid;
    int row = li >> 3, col = (li & 7) * 8;
    bf16v8 val = *(const bf16v8*)(v + base + (size_t)(t0 + row) * HDIM + col);
    #pragma unroll
    for (int j = 0; j < 8; ++j) tile[(col + j) * 72 + row] = val[j];
  }
  __syncthreads();
  #pragma unroll
  for (int r = 0; r < 2; ++r) {
    int li = r * 256 + tid;
    int drow = li >> 3, tcol = (li & 7) * 8;
    bf16v8 val;
    #pragma unroll
    for (int j = 0; j < 8; ++j) val[j] = tile[drow * 72 + tcol + j];
    *(bf16v8*)(vt + base + (size_t)drow * SEQ + t0 + tcol) = val;
  }
}

// ---------------- Flash attention v4 ----------------
// = v3 (LDS overlay 41 KB, ones-column row-sum, log2-domain scores) but with
// __launch_bounds__(512,4): round 3's (512,6) forced VGPR<=~85 and the
// compiler SPILLED (WRITE_SIZE 16->74 MB, FETCH +210 MB) — net regression.
// Occupancy comes from actual usage (~64 VGPR) + 41 KB LDS -> 3 blocks/CU.

__launch_bounds__(512, 4)
__global__ void attn_kernel(const bf16* __restrict__ qh, const bf16* __restrict__ ql,
                            const bf16* __restrict__ kh, const bf16* __restrict__ kl,
                            const bf16* __restrict__ vt, bf16* __restrict__ o) {
  __shared__ __align__(16) char smem[41984];
  bf16* Qh = (bf16*)smem;               // 16384 B   (Q phase)
  bf16* Ql = (bf16*)(smem + 16384);     // 16384 B
  bf16* Kh = (bf16*)smem;               // 8192 B    (K phase, aliases Q)
  bf16* Kl = (bf16*)(smem + 8192);      // 8192 B
  bf16* Vt = (bf16*)(smem + 16384);     // 8192 B
  bf16* Pw = (bf16*)(smem + 24576);     // 8 waves * 16*68*2 = 17408 B
  const int tid = threadIdx.x;
  const int lane = tid & 63, wid = tid >> 6;
  const int quad = lane >> 4, l16 = lane & 15;
  const int xs = l16 & 7;
  const int bh = blockIdx.y;
  const int qt = (int)gridDim.x - 1 - (int)blockIdx.x;   // heavy first
  const int q0 = qt * 128;
  const size_t base = (size_t)bh * SEQ * HDIM;

  // stage Q (hi+lo), swizzled
  #pragma unroll
  for (int r = 0; r < 2; ++r) {
    int li = r * 512 + tid;
    int row = li >> 3, cg = (li & 7) ^ (row & 7);
    gload_lds16(qh + base + (size_t)(q0 + row) * HDIM + cg * 8, &Qh[li * 8]);
    gload_lds16(ql + base + (size_t)(q0 + row) * HDIM + cg * 8, &Ql[li * 8]);
  }
  __syncthreads();
  bf16v8 qhf[2], qlf[2];
  #pragma unroll
  for (int kk = 0; kk < 2; ++kk) {
    int off = (wid * 16 + l16) * 64 + (((kk << 2) | quad) ^ xs) * 8;
    qhf[kk] = *(const bf16v8*)&Qh[off];
    qlf[kk] = *(const bf16v8*)&Ql[off];
  }

  bf16v8 ones_f;
  {
    bf16 v1 = (l16 == 0) ? (bf16)1.0f : (bf16)0.0f;
    #pragma unroll
    for (int j = 0; j < 8; ++j) ones_f[j] = v1;
  }

  f32v4 oacc[4] = {};
  f32v4 lacc = {};
  float mrow[4];
  #pragma unroll
  for (int r = 0; r < 4; ++r) mrow[r] = -1e30f;

  const int qrow_hi = q0 + wid * 16 + 15;       // wave-uniform causal limit
  const int ntiles = 2 * qt + 2;
  for (int ktile = 0; ktile < ntiles; ++ktile) {
    const int k0 = ktile * 64;
    __syncthreads();                            // also protects Q->K overlay on iter 0
    {
      int row = tid >> 3, cg = (tid & 7) ^ (row & 7);
      gload_lds16(kh + base + (size_t)(k0 + row) * HDIM + cg * 8, &Kh[(size_t)tid * 8]);
      gload_lds16(kl + base + (size_t)(k0 + row) * HDIM + cg * 8, &Kl[(size_t)tid * 8]);
      gload_lds16(vt + base + (size_t)row * SEQ + k0 + cg * 8,    &Vt[(size_t)tid * 8]);
    }
    __syncthreads();
    if (k0 > qrow_hi) continue;                  // fully-masked tile for this wave

    f32v4 sacc[4] = {};
    #pragma unroll
    for (int kk = 0; kk < 2; ++kk) {
      const int co = (((kk << 2) | quad) ^ xs) * 8;
      bf16v8 khf[4], klf[4];
      #pragma unroll
      for (int nt = 0; nt < 4; ++nt) {
        khf[nt] = *(const bf16v8*)&Kh[(nt * 16 + l16) * 64 + co];
        klf[nt] = *(const bf16v8*)&Kl[(nt * 16 + l16) * 64 + co];
      }
      #pragma unroll
      for (int nt = 0; nt < 4; ++nt) {
        sacc[nt] = MFMA16(qhf[kk], khf[nt], sacc[nt]);
        sacc[nt] = MFMA16(qhf[kk], klf[nt], sacc[nt]);
        sacc[nt] = MFMA16(qlf[kk], khf[nt], sacc[nt]);
      }
    }

    // mask (scores already in log2 domain)
    const int qrow_base = q0 + wid * 16 + quad * 4;
    #pragma unroll
    for (int nt = 0; nt < 4; ++nt) {
      int key = k0 + nt * 16 + l16;
      #pragma unroll
      for (int r = 0; r < 4; ++r)
        if (key > qrow_base + r) sacc[nt][r] = -1e30f;
    }
    float mnew[4], alpha[4];
    #pragma unroll
    for (int r = 0; r < 4; ++r) {
      float mx = fmaxf(fmaxf(sacc[0][r], sacc[1][r]), fmaxf(sacc[2][r], sacc[3][r]));
      #pragma unroll
      for (int off = 8; off; off >>= 1) mx = fmaxf(mx, __shfl_xor(mx, off, 64));
      mnew[r] = fmaxf(mrow[r], mx);
      alpha[r] = __builtin_amdgcn_exp2f(mrow[r] - mnew[r]);
      mrow[r] = mnew[r];
    }
    bf16* pwave = Pw + wid * (16 * 68);
    #pragma unroll
    for (int nt = 0; nt < 4; ++nt)
      #pragma unroll
      for (int r = 0; r < 4; ++r)
        pwave[(quad * 4 + r) * 68 + nt * 16 + l16] =
            (bf16)__builtin_amdgcn_exp2f(sacc[nt][r] - mnew[r]);
    #pragma unroll
    for (int r = 0; r < 4; ++r) {
      lacc[r] *= alpha[r];
      #pragma unroll
      for (int dt = 0; dt < 4; ++dt) oacc[dt][r] *= alpha[r];
    }

    // PV + row-sum (ones-column): A = P (wave-private LDS slice)
    #pragma unroll
    for (int kk = 0; kk < 2; ++kk) {
      bf16v8 pf = *(const bf16v8*)&pwave[l16 * 68 + kk * 32 + quad * 8];
      const int co = (((kk << 2) | quad) ^ xs) * 8;
      lacc = MFMA16(pf, ones_f, lacc);
      #pragma unroll
      for (int dt = 0; dt < 4; ++dt) {
        bf16v8 vf = *(const bf16v8*)&Vt[(dt * 16 + l16) * 64 + co];
        oacc[dt] = MFMA16(pf, vf, oacc[dt]);
      }
    }
  }

  // row-sum lives in column 0 (lane l16==0 of each quad) -> broadcast
  float lrow[4];
  #pragma unroll
  for (int r = 0; r < 4; ++r) lrow[r] = __shfl(lacc[r], lane & 48, 64);

  const int b = bh >> 4, h = bh & 15;
  #pragma unroll
  for (int dt = 0; dt < 4; ++dt)
    #pragma unroll
    for (int r = 0; r < 4; ++r) {
      int q = q0 + wid * 16 + quad * 4 + r;
      int d = dt * 16 + l16;
      float val = oacc[dt][r] / lrow[r];
      o[((size_t)(b * SEQ + q)) * EMB + h * HDIM + d] = (bf16)val;
    }
}

// ---------------- out projection (unchanged) ----------------

__launch_bounds__(256, 2)
__global__ void gemm_out_kernel(const bf16* __restrict__ oin, const bf16* __restrict__ wt,
                                float* __restrict__ out) {
  __shared__ __align__(16) bf16 As_[128 * 64];
  __shared__ __align__(16) bf16 Bs_[128 * 64];
  const int tid = threadIdx.x;
  const int lane = tid & 63, wid = tid >> 6;
  const int quad = lane >> 4, l16 = lane & 15;
  const int m0 = blockIdx.x * 128, n0 = blockIdx.y * 128;
  const int wm = (wid >> 1) * 64, wn = (wid & 1) * 64;
  f32v4 acc[4][4] = {};

  for (int kt = 0; kt < EMB / 64; ++kt) {
    __syncthreads();
    #pragma unroll
    for (int r = 0; r < 4; ++r) {
      int li = r * 256 + tid;
      int row = li >> 3, col = (li & 7) * 8;
      gload_lds16(oin + (size_t)(m0 + row) * EMB + kt * 64 + col, &As_[li * 8]);
      gload_lds16(wt  + (size_t)(n0 + row) * EMB + kt * 64 + col, &Bs_[li * 8]);
    }
    __syncthreads();
    #pragma unroll
    for (int kk = 0; kk < 2; ++kk) {
      bf16v8 af[4], bfr[4];
      #pragma unroll
      for (int i = 0; i < 4; ++i) {
        af[i]  = *(const bf16v8*)&As_[(wm + i * 16 + l16) * 64 + kk * 32 + quad * 8];
        bfr[i] = *(const bf16v8*)&Bs_[(wn + i * 16 + l16) * 64 + kk * 32 + quad * 8];
      }
      #pragma unroll
      for (int i = 0; i < 4; ++i)
        #pragma unroll
        for (int j = 0; j < 4; ++j)
          acc[i][j] = MFMA16(af[i], bfr[j], acc[i][j]);
    }
  }
  #pragma unroll
  for (int i = 0; i < 4; ++i)
    #pragma unroll
    for (int j = 0; j < 4; ++j)
      #pragma unroll
      for (int r = 0; r < 4; ++r) {
        int m = m0 + wm + i * 16 + quad * 4 + r;
        int n = n0 + wn + j * 16 + l16;
        out[(size_t)m * EMB + n] = acc[i][j][r];
      }
}

// ---------------- launch ----------------

extern "C" void kernel_launch(void* const* d_in, const int* in_sizes, int n_in,
                              void* d_out, int out_size, void* d_ws, size_t ws_size,
                              hipStream_t stream) {
  const float* x     = (const float*)d_in[0];
  const float* w_qkv = (const float*)d_in[1];
  const float* w_out = (const float*)d_in[2];
  float* out = (float*)d_out;
  char* ws = (char*)d_ws;

  const size_t SZ = (size_t)MROWS * EMB * sizeof(bf16);   // 16.78 MB
  size_t off = 0;
  float* sums = (float*)ws;            off = 256;
  bf16* wq_t = (bf16*)(ws + off);      off += (size_t)NQKV * EMB * sizeof(bf16);
  bf16* wo_t = (bf16*)(ws + off);      off += (size_t)EMB * EMB * sizeof(bf16);
  bf16* xh   = (bf16*)(ws + off);      off += SZ;
  bf16* xl   = (bf16*)(ws + off);      off += SZ;
  bf16* qh   = (bf16*)(ws + off);      off += SZ;
  bf16* ql   = (bf16*)(ws + off);      off += SZ;
  bf16* kh   = (bf16*)(ws + off);      off += SZ;
  bf16* kl   = (bf16*)(ws + off);      off += SZ;
  bf16* vv   = (bf16*)(ws + off);      off += SZ;
  bf16* vt   = xh;   // x dead after gemm_qkv -> reuse
  bf16* ob   = xl;   // attention output (bf16), reuse
  (void)in_sizes; (void)n_in; (void)out_size; (void)ws_size;

  zero2_kernel<<<1, 2, 0, stream>>>(sums);
  abs_sum_kernel<<<256, 256, 0, stream>>>(w_qkv, NQKV * EMB, &sums[0]);
  abs_sum_kernel<<<256, 256, 0, stream>>>(w_out, EMB * EMB, &sums[1]);
  ternarize_kernel<<<(NQKV * EMB) / 256, 256, 0, stream>>>(w_qkv, NQKV * EMB, &sums[0], wq_t);
  ternarize_kernel<<<(EMB * EMB) / 256, 256, 0, stream>>>(w_out, EMB * EMB, &sums[1], wo_t);
  split_x_kernel<<<(MROWS * EMB) / 256, 256, 0, stream>>>(x, xh, xl, MROWS * EMB);
  gemm_qkv_kernel<<<dim3(MROWS / 128, NQKV / 128), 256, 0, stream>>>(xh, xl, wq_t, qh, ql, kh, kl, vv);
  transpose_v_kernel<<<dim3(SEQ / 64, BSZ * NHEAD), 256, 0, stream>>>(vv, vt);
  attn_kernel<<<dim3(SEQ / 128, BSZ * NHEAD), 512, 0, stream>>>(qh, ql, kh, kl, vt, ob);
  gemm_out_kernel<<<dim3(MROWS / 128, EMB / 128), 256, 0, stream>>>(ob, wo_t, out);
}

// Round 5
// 389.517 us; speedup vs baseline: 1.4693x; 1.2383x over previous
//
#include <hip/hip_runtime.h>
#include <hip/hip_bf16.h>

#define EMB   1024
#define NHEAD 16
#define HDIM  64
#define BSZ   4
#define SEQ   2048
#define MROWS (BSZ*SEQ)     // 8192
#define NQKV  (3*EMB)       // 3072

typedef __bf16 bf16;
typedef __bf16 bf16v8 __attribute__((ext_vector_type(8)));
typedef float  f32v4  __attribute__((ext_vector_type(4)));

#define MFMA16(a,b,c) __builtin_amdgcn_mfma_f32_16x16x32_bf16((a),(b),(c),0,0,0)

__device__ __forceinline__ void gload_lds16(const bf16* g, bf16* l) {
  __builtin_amdgcn_global_load_lds((const __attribute__((address_space(1))) void*)g,
                                   (__attribute__((address_space(3))) void*)l,
                                   16, 0, 0);
}

// ---------------- scale reduction + ternarize + split ----------------

__global__ void zero2_kernel(float* p) { p[threadIdx.x] = 0.f; }

__global__ void abs_sum_kernel(const float* __restrict__ w, int n, float* out) {
  float s = 0.f;
  for (int i = blockIdx.x * blockDim.x + threadIdx.x; i < n; i += gridDim.x * blockDim.x)
    s += fabsf(w[i]);
  #pragma unroll
  for (int off = 32; off; off >>= 1) s += __shfl_down(s, off, 64);
  __shared__ float red[4];
  int lane = threadIdx.x & 63, wid = threadIdx.x >> 6;
  if (lane == 0) red[wid] = s;
  __syncthreads();
  if (threadIdx.x == 0) atomicAdd(out, red[0] + red[1] + red[2] + red[3]);
}

__global__ void ternarize_kernel(const float* __restrict__ w, int n,
                                 const float* __restrict__ sum, bf16* __restrict__ out) {
  int i = blockIdx.x * blockDim.x + threadIdx.x;
  if (i >= n) return;
  float scale = fmaxf(*sum / (float)n, 1e-8f);
  float t = rintf(w[i] / scale);          // RNE == jnp.round
  t = fmaxf(-1.f, fminf(1.f, t));
  out[i] = (bf16)t;                        // {-1,0,1} exact in bf16
}

__global__ void split_x_kernel(const float* __restrict__ x, bf16* __restrict__ xh,
                               bf16* __restrict__ xl, int n) {
  int i = blockIdx.x * blockDim.x + threadIdx.x;
  if (i >= n) return;
  float v = x[i];
  bf16 h = (bf16)v;
  xh[i] = h;
  xl[i] = (bf16)(v - (float)h);
}

// ---------------- QKV GEMM ----------------
// q pre-scaled by 0.125*log2(e) so attn softmax works directly in log2 domain.
// v-region blocks (n0 >= 2048, block-uniform) skip the lo-half A staging and
// MFMAs: v only needs single-bf16 accuracy (it feeds bf16 PV anyway).

__launch_bounds__(256, 2)
__global__ void gemm_qkv_kernel(const bf16* __restrict__ xh, const bf16* __restrict__ xl,
                                const bf16* __restrict__ wt,
                                bf16* __restrict__ qh, bf16* __restrict__ ql,
                                bf16* __restrict__ kh, bf16* __restrict__ kl,
                                bf16* __restrict__ vv) {
  __shared__ __align__(16) bf16 Ah[128 * 64];
  __shared__ __align__(16) bf16 Al[128 * 64];
  __shared__ __align__(16) bf16 Bs[128 * 64];
  const int tid = threadIdx.x;
  const int lane = tid & 63, wid = tid >> 6;
  const int quad = lane >> 4, l16 = lane & 15;
  const int m0 = blockIdx.x * 128, n0 = blockIdx.y * 128;
  const int wm = (wid >> 1) * 64, wn = (wid & 1) * 64;
  const bool vblk = (n0 >= 2 * EMB);       // block-uniform
  f32v4 acc[4][4] = {};

  for (int kt = 0; kt < EMB / 64; ++kt) {
    __syncthreads();
    #pragma unroll
    for (int r = 0; r < 4; ++r) {
      int li = r * 256 + tid;
      int row = li >> 3, col = (li & 7) * 8;
      gload_lds16(xh + (size_t)(m0 + row) * EMB + kt * 64 + col, &Ah[li * 8]);
      if (!vblk)
        gload_lds16(xl + (size_t)(m0 + row) * EMB + kt * 64 + col, &Al[li * 8]);
      gload_lds16(wt + (size_t)(n0 + row) * EMB + kt * 64 + col, &Bs[li * 8]);
    }
    __syncthreads();
    #pragma unroll
    for (int kk = 0; kk < 2; ++kk) {
      bf16v8 af[4], alf[4], bfr[4];
      #pragma unroll
      for (int i = 0; i < 4; ++i) {
        af[i]  = *(const bf16v8*)&Ah[(wm + i * 16 + l16) * 64 + kk * 32 + quad * 8];
        if (!vblk)
          alf[i] = *(const bf16v8*)&Al[(wm + i * 16 + l16) * 64 + kk * 32 + quad * 8];
        bfr[i] = *(const bf16v8*)&Bs[(wn + i * 16 + l16) * 64 + kk * 32 + quad * 8];
      }
      #pragma unroll
      for (int i = 0; i < 4; ++i)
        #pragma unroll
        for (int j = 0; j < 4; ++j) {
          acc[i][j] = MFMA16(af[i], bfr[j], acc[i][j]);
          if (!vblk) acc[i][j] = MFMA16(alf[i], bfr[j], acc[i][j]);
        }
    }
  }
  const float QSCALE = 0.18033688011112042f;   // 0.125 * log2(e)
  #pragma unroll
  for (int i = 0; i < 4; ++i)
    #pragma unroll
    for (int j = 0; j < 4; ++j)
      #pragma unroll
      for (int r = 0; r < 4; ++r) {
        int m = m0 + wm + i * 16 + quad * 4 + r;
        int n = n0 + wn + j * 16 + l16;
        float c = acc[i][j][r];
        int b = m >> 11, t = m & (SEQ - 1);
        int region = n >> 10, c1 = n & 1023, h = c1 >> 6, d = c1 & 63;
        size_t idx = (((size_t)(b * NHEAD + h) * SEQ + t) << 6) + d;
        if (region == 0)      { float cs = c * QSCALE; bf16 hi = (bf16)cs; qh[idx] = hi; ql[idx] = (bf16)(cs - (float)hi); }
        else if (region == 1) { bf16 hi = (bf16)c; kh[idx] = hi; kl[idx] = (bf16)(c - (float)hi); }
        else                  { vv[idx] = (bf16)c; }
      }
}

// ---------------- V transpose: [B,H,T,D] -> [B,H,D,T] ----------------

__global__ void transpose_v_kernel(const bf16* __restrict__ v, bf16* __restrict__ vt) {
  __shared__ bf16 tile[64 * 72];
  const int tid = threadIdx.x;
  const int bh = blockIdx.y, t0 = blockIdx.x * 64;
  const size_t base = (size_t)bh * SEQ * HDIM;
  #pragma unroll
  for (int r = 0; r < 2; ++r) {
    int li = r * 256 + tid;
    int row = li >> 3, col = (li & 7) * 8;
    bf16v8 val = *(const bf16v8*)(v + base + (size_t)(t0 + row) * HDIM + col);
    #pragma unroll
    for (int j = 0; j < 8; ++j) tile[(col + j) * 72 + row] = val[j];
  }
  __syncthreads();
  #pragma unroll
  for (int r = 0; r < 2; ++r) {
    int li = r * 256 + tid;
    int drow = li >> 3, tcol = (li & 7) * 8;
    bf16v8 val;
    #pragma unroll
    for (int j = 0; j < 8; ++j) val[j] = tile[drow * 72 + tcol + j];
    *(bf16v8*)(vt + base + (size_t)drow * SEQ + t0 + tcol) = val;
  }
}

// ---------------- Flash attention v5 ----------------
// = v4 (overlay 41 KB, ones-column row-sum, log2-domain scores, (512,4))
// + uniform-work pairing: block (pair,bh) processes q-tile 8+pair (heavy)
// then 7-pair (light): (2*qt1+2)+(2*qt2+2) = 34 key-tiles for EVERY block.
// Grid 8x64 = 512 uniform blocks -> single dispatch round, 2 blocks/CU,
// no causal tail imbalance (round-4 occupancy was 21% on a 16:1-variance
// 1024-block grid). Q restaged per phase into the overlay region (barrier-
// protected; P slices are written fresh each tile so the clobber is dead data).

__launch_bounds__(512, 4)
__global__ void attn_kernel(const bf16* __restrict__ qh, const bf16* __restrict__ ql,
                            const bf16* __restrict__ kh, const bf16* __restrict__ kl,
                            const bf16* __restrict__ vt, bf16* __restrict__ o) {
  __shared__ __align__(16) char smem[41984];
  bf16* Qh = (bf16*)smem;               // 16384 B   (Q phase)
  bf16* Ql = (bf16*)(smem + 16384);     // 16384 B
  bf16* Kh = (bf16*)smem;               // 8192 B    (K phase, aliases Q)
  bf16* Kl = (bf16*)(smem + 8192);      // 8192 B
  bf16* Vt = (bf16*)(smem + 16384);     // 8192 B
  bf16* Pw = (bf16*)(smem + 24576);     // 8 waves * 16*68*2 = 17408 B
  const int tid = threadIdx.x;
  const int lane = tid & 63, wid = tid >> 6;
  const int quad = lane >> 4, l16 = lane & 15;
  const int xs = l16 & 7;
  const int pair = blockIdx.x;          // 0..7
  const int bh = blockIdx.y;
  const size_t base = (size_t)bh * SEQ * HDIM;

  bf16v8 ones_f;
  {
    bf16 v1 = (l16 == 0) ? (bf16)1.0f : (bf16)0.0f;
    #pragma unroll
    for (int j = 0; j < 8; ++j) ones_f[j] = v1;
  }
  const int b = bh >> 4, h = bh & 15;

  for (int phase = 0; phase < 2; ++phase) {
    const int qt = phase ? (7 - pair) : (8 + pair);
    const int q0 = qt * 128;

    __syncthreads();                    // prior phase's LDS readers done
    // stage Q (hi+lo), swizzled
    #pragma unroll
    for (int r = 0; r < 2; ++r) {
      int li = r * 512 + tid;
      int row = li >> 3, cg = (li & 7) ^ (row & 7);
      gload_lds16(qh + base + (size_t)(q0 + row) * HDIM + cg * 8, &Qh[li * 8]);
      gload_lds16(ql + base + (size_t)(q0 + row) * HDIM + cg * 8, &Ql[li * 8]);
    }
    __syncthreads();
    bf16v8 qhf[2], qlf[2];
    #pragma unroll
    for (int kk = 0; kk < 2; ++kk) {
      int off = (wid * 16 + l16) * 64 + (((kk << 2) | quad) ^ xs) * 8;
      qhf[kk] = *(const bf16v8*)&Qh[off];
      qlf[kk] = *(const bf16v8*)&Ql[off];
    }

    f32v4 oacc[4] = {};
    f32v4 lacc = {};
    float mrow[4];
    #pragma unroll
    for (int r = 0; r < 4; ++r) mrow[r] = -1e30f;

    const int qrow_hi = q0 + wid * 16 + 15;     // wave-uniform causal limit
    const int ntiles = 2 * qt + 2;
    for (int ktile = 0; ktile < ntiles; ++ktile) {
      const int k0 = ktile * 64;
      __syncthreads();                          // Q->K overlay / prev-iter readers
      {
        int row = tid >> 3, cg = (tid & 7) ^ (row & 7);
        gload_lds16(kh + base + (size_t)(k0 + row) * HDIM + cg * 8, &Kh[(size_t)tid * 8]);
        gload_lds16(kl + base + (size_t)(k0 + row) * HDIM + cg * 8, &Kl[(size_t)tid * 8]);
        gload_lds16(vt + base + (size_t)row * SEQ + k0 + cg * 8,    &Vt[(size_t)tid * 8]);
      }
      __syncthreads();
      if (k0 > qrow_hi) continue;               // fully-masked tile for this wave

      f32v4 sacc[4] = {};
      #pragma unroll
      for (int kk = 0; kk < 2; ++kk) {
        const int co = (((kk << 2) | quad) ^ xs) * 8;
        bf16v8 khf[4], klf[4];
        #pragma unroll
        for (int nt = 0; nt < 4; ++nt) {
          khf[nt] = *(const bf16v8*)&Kh[(nt * 16 + l16) * 64 + co];
          klf[nt] = *(const bf16v8*)&Kl[(nt * 16 + l16) * 64 + co];
        }
        #pragma unroll
        for (int nt = 0; nt < 4; ++nt) {
          sacc[nt] = MFMA16(qhf[kk], khf[nt], sacc[nt]);
          sacc[nt] = MFMA16(qhf[kk], klf[nt], sacc[nt]);
          sacc[nt] = MFMA16(qlf[kk], khf[nt], sacc[nt]);
        }
      }

      // mask (scores already in log2 domain)
      const int qrow_base = q0 + wid * 16 + quad * 4;
      #pragma unroll
      for (int nt = 0; nt < 4; ++nt) {
        int key = k0 + nt * 16 + l16;
        #pragma unroll
        for (int r = 0; r < 4; ++r)
          if (key > qrow_base + r) sacc[nt][r] = -1e30f;
      }
      float mnew[4], alpha[4];
      #pragma unroll
      for (int r = 0; r < 4; ++r) {
        float mx = fmaxf(fmaxf(sacc[0][r], sacc[1][r]), fmaxf(sacc[2][r], sacc[3][r]));
        #pragma unroll
        for (int off = 8; off; off >>= 1) mx = fmaxf(mx, __shfl_xor(mx, off, 64));
        mnew[r] = fmaxf(mrow[r], mx);
        alpha[r] = __builtin_amdgcn_exp2f(mrow[r] - mnew[r]);
        mrow[r] = mnew[r];
      }
      bf16* pwave = Pw + wid * (16 * 68);
      #pragma unroll
      for (int nt = 0; nt < 4; ++nt)
        #pragma unroll
        for (int r = 0; r < 4; ++r)
          pwave[(quad * 4 + r) * 68 + nt * 16 + l16] =
              (bf16)__builtin_amdgcn_exp2f(sacc[nt][r] - mnew[r]);
      #pragma unroll
      for (int r = 0; r < 4; ++r) {
        lacc[r] *= alpha[r];
        #pragma unroll
        for (int dt = 0; dt < 4; ++dt) oacc[dt][r] *= alpha[r];
      }

      // PV + row-sum (ones-column): A = P (wave-private LDS slice)
      #pragma unroll
      for (int kk = 0; kk < 2; ++kk) {
        bf16v8 pf = *(const bf16v8*)&pwave[l16 * 68 + kk * 32 + quad * 8];
        const int co = (((kk << 2) | quad) ^ xs) * 8;
        lacc = MFMA16(pf, ones_f, lacc);
        #pragma unroll
        for (int dt = 0; dt < 4; ++dt) {
          bf16v8 vf = *(const bf16v8*)&Vt[(dt * 16 + l16) * 64 + co];
          oacc[dt] = MFMA16(pf, vf, oacc[dt]);
        }
      }
    }

    // row-sum lives in column 0 (lane l16==0 of each quad) -> broadcast
    float lrow[4];
    #pragma unroll
    for (int r = 0; r < 4; ++r) lrow[r] = __shfl(lacc[r], lane & 48, 64);

    #pragma unroll
    for (int dt = 0; dt < 4; ++dt)
      #pragma unroll
      for (int r = 0; r < 4; ++r) {
        int q = q0 + wid * 16 + quad * 4 + r;
        int d = dt * 16 + l16;
        float val = oacc[dt][r] / lrow[r];
        o[((size_t)(b * SEQ + q)) * EMB + h * HDIM + d] = (bf16)val;
      }
  }
}

// ---------------- out projection (unchanged) ----------------

__launch_bounds__(256, 2)
__global__ void gemm_out_kernel(const bf16* __restrict__ oin, const bf16* __restrict__ wt,
                                float* __restrict__ out) {
  __shared__ __align__(16) bf16 As_[128 * 64];
  __shared__ __align__(16) bf16 Bs_[128 * 64];
  const int tid = threadIdx.x;
  const int lane = tid & 63, wid = tid >> 6;
  const int quad = lane >> 4, l16 = lane & 15;
  const int m0 = blockIdx.x * 128, n0 = blockIdx.y * 128;
  const int wm = (wid >> 1) * 64, wn = (wid & 1) * 64;
  f32v4 acc[4][4] = {};

  for (int kt = 0; kt < EMB / 64; ++kt) {
    __syncthreads();
    #pragma unroll
    for (int r = 0; r < 4; ++r) {
      int li = r * 256 + tid;
      int row = li >> 3, col = (li & 7) * 8;
      gload_lds16(oin + (size_t)(m0 + row) * EMB + kt * 64 + col, &As_[li * 8]);
      gload_lds16(wt  + (size_t)(n0 + row) * EMB + kt * 64 + col, &Bs_[li * 8]);
    }
    __syncthreads();
    #pragma unroll
    for (int kk = 0; kk < 2; ++kk) {
      bf16v8 af[4], bfr[4];
      #pragma unroll
      for (int i = 0; i < 4; ++i) {
        af[i]  = *(const bf16v8*)&As_[(wm + i * 16 + l16) * 64 + kk * 32 + quad * 8];
        bfr[i] = *(const bf16v8*)&Bs_[(wn + i * 16 + l16) * 64 + kk * 32 + quad * 8];
      }
      #pragma unroll
      for (int i = 0; i < 4; ++i)
        #pragma unroll
        for (int j = 0; j < 4; ++j)
          acc[i][j] = MFMA16(af[i], bfr[j], acc[i][j]);
    }
  }
  #pragma unroll
  for (int i = 0; i < 4; ++i)
    #pragma unroll
    for (int j = 0; j < 4; ++j)
      #pragma unroll
      for (int r = 0; r < 4; ++r) {
        int m = m0 + wm + i * 16 + quad * 4 + r;
        int n = n0 + wn + j * 16 + l16;
        out[(size_t)m * EMB + n] = acc[i][j][r];
      }
}

// ---------------- launch ----------------

extern "C" void kernel_launch(void* const* d_in, const int* in_sizes, int n_in,
                              void* d_out, int out_size, void* d_ws, size_t ws_size,
                              hipStream_t stream) {
  const float* x     = (const float*)d_in[0];
  const float* w_qkv = (const float*)d_in[1];
  const float* w_out = (const float*)d_in[2];
  float* out = (float*)d_out;
  char* ws = (char*)d_ws;

  const size_t SZ = (size_t)MROWS * EMB * sizeof(bf16);   // 16.78 MB
  size_t off = 0;
  float* sums = (float*)ws;            off = 256;
  bf16* wq_t = (bf16*)(ws + off);      off += (size_t)NQKV * EMB * sizeof(bf16);
  bf16* wo_t = (bf16*)(ws + off);      off += (size_t)EMB * EMB * sizeof(bf16);
  bf16* xh   = (bf16*)(ws + off);      off += SZ;
  bf16* xl   = (bf16*)(ws + off);      off += SZ;
  bf16* qh   = (bf16*)(ws + off);      off += SZ;
  bf16* ql   = (bf16*)(ws + off);      off += SZ;
  bf16* kh   = (bf16*)(ws + off);      off += SZ;
  bf16* kl   = (bf16*)(ws + off);      off += SZ;
  bf16* vv   = (bf16*)(ws + off);      off += SZ;
  bf16* vt   = xh;   // x dead after gemm_qkv -> reuse
  bf16* ob   = xl;   // attention output (bf16), reuse
  (void)in_sizes; (void)n_in; (void)out_size; (void)ws_size;

  zero2_kernel<<<1, 2, 0, stream>>>(sums);
  abs_sum_kernel<<<256, 256, 0, stream>>>(w_qkv, NQKV * EMB, &sums[0]);
  abs_sum_kernel<<<256, 256, 0, stream>>>(w_out, EMB * EMB, &sums[1]);
  ternarize_kernel<<<(NQKV * EMB) / 256, 256, 0, stream>>>(w_qkv, NQKV * EMB, &sums[0], wq_t);
  ternarize_kernel<<<(EMB * EMB) / 256, 256, 0, stream>>>(w_out, EMB * EMB, &sums[1], wo_t);
  split_x_kernel<<<(MROWS * EMB) / 256, 256, 0, stream>>>(x, xh, xl, MROWS * EMB);
  gemm_qkv_kernel<<<dim3(MROWS / 128, NQKV / 128), 256, 0, stream>>>(xh, xl, wq_t, qh, ql, kh, kl, vv);
  transpose_v_kernel<<<dim3(SEQ / 64, BSZ * NHEAD), 256, 0, stream>>>(vv, vt);
  attn_kernel<<<dim3(8, BSZ * NHEAD), 512, 0, stream>>>(qh, ql, kh, kl, vt, ob);
  gemm_out_kernel<<<dim3(MROWS / 128, EMB / 128), 256, 0, stream>>>(ob, wo_t, out);
}